// Round 12
// baseline (389.044 us; speedup 1.0000x reference)
//
#include <hip/hip_runtime.h>
#include <stdint.h>
#include <math.h>

#define T_SEQ 2048
#define NHEAD 16
#define HD 64
#define DMODEL 1024
#define CDIM 1088
#define MROWS 4096

typedef uint16_t u16;
typedef __bf16 b8v __attribute__((ext_vector_type(8)));
typedef float f4v __attribute__((ext_vector_type(4)));

typedef __attribute__((address_space(3))) void lds_void;
typedef const __attribute__((address_space(1))) void glb_void;

#define GLL(g, l) __builtin_amdgcn_global_load_lds((glb_void*)(g), (lds_void*)(l), 16, 0, 0)
// raw HW barrier (opaque to compiler reordering via "memory" clobber)
#define ABAR() asm volatile("s_barrier" ::: "memory")

__device__ __forceinline__ u16 f2b(float f) {
  union { float f; uint32_t i; } c; c.f = f;
  uint32_t x = c.i;
  return (u16)((x + 0x7fffu + ((x >> 16) & 1u)) >> 16);
}
// packed f32x2 -> bf16x2 (RNE) in one instruction; no builtin on gfx950 (m240)
__device__ __forceinline__ uint32_t cvt_pk_bf16(float lo, float hi) {
  uint32_t r;
  asm("v_cvt_pk_bf16_f32 %0, %1, %2" : "=v"(r) : "v"(lo), "v"(hi));
  return r;
}
// hardware 2^x (v_exp_f32); avoids glibc __exp2f macro collision
__device__ __forceinline__ float exp2_hw(float x) {
  return __builtin_amdgcn_exp2f(x);
}
// Fast exact-GELU: erf via Abramowitz-Stegun 7.1.26 (max abs err 1.5e-7).
__device__ __forceinline__ float gelu_f(float x) {
  float ax = fabsf(x);
  float xs = ax * 0.70710678118654752f;
  float t = __frcp_rn(1.0f + 0.3275911f * xs);
  float poly = ((((1.061405429f * t - 1.453152027f) * t + 1.421413741f) * t
                 - 0.284496736f) * t + 0.254829592f) * t;
  float e = __expf(-xs * xs);
  float er = 1.0f - poly * e;
  er = copysignf(er, x);
  return 0.5f * x * (1.0f + er);
}

// ---------------- time MLP (f32 in, f32 out) ---------------------------------
__global__ void time_mlp_kernel(const float* __restrict__ t, const float* __restrict__ w1,
                                const float* __restrict__ b1, const float* __restrict__ w2,
                                const float* __restrict__ b2, float* __restrict__ temb) {
  __shared__ float h1[2][64];
  int tid = threadIdx.x;            // 128 threads
  int b = tid >> 6, i = tid & 63;
  float tv = t[b];
  h1[b][i] = gelu_f(tv * w1[i] + b1[i]);
  __syncthreads();
  float acc = b2[i];
  for (int k = 0; k < 64; ++k) acc += h1[b][k] * w2[k * 64 + i];
  temb[b * 64 + i] = acc;
}

// ---------------- transpose + cast: src f32[R][C] -> dst bf16[C][R] ----------
__global__ __launch_bounds__(256) void transpose_kernel(const float* __restrict__ src,
                                                        u16* __restrict__ dst,
                                                        int R, int C) {
  __shared__ u16 tile[32][33];
  int tx = threadIdx.x & 31, ty = threadIdx.x >> 5;   // ty 0..7
  int c0 = blockIdx.x * 32, r0 = blockIdx.y * 32;
#pragma unroll
  for (int i = 0; i < 4; ++i) {
    int r = ty + i * 8;
    tile[r][tx] = f2b(src[(size_t)(r0 + r) * C + c0 + tx]);
  }
  __syncthreads();
#pragma unroll
  for (int i = 0; i < 4; ++i) {
    int c = ty + i * 8;
    dst[(size_t)(c0 + c) * R + r0 + tx] = tile[tx][c];
  }
}

// ---------------- add four f32 buffers -> f32 out (fc2 split-K reduce) -------
__global__ __launch_bounds__(256) void add4_kernel(const float4* __restrict__ a,
                                                   const float4* __restrict__ b,
                                                   const float4* __restrict__ c,
                                                   const float4* __restrict__ d,
                                                   float4* __restrict__ o, int n4) {
  int i = blockIdx.x * 256 + threadIdx.x;
  if (i < n4) {
    float4 x = a[i], y = b[i], z = c[i], w = d[i];
    o[i] = float4{x.x + y.x + z.x + w.x, x.y + y.y + z.y + w.y,
                  x.z + y.z + z.z + w.z, x.w + y.w + z.w + w.w};
  }
}

// ---------------- fused concat + LayerNorm -> bf16 ---------------------------
// mode 1: z from zf (f32); mode 2: z = zf + zf2 (f32)
__global__ __launch_bounds__(256) void ln_concat_kernel(const float* __restrict__ zf,
                                                        const float* __restrict__ zf2,
                                                        const float* __restrict__ temb,
                                                        const float* __restrict__ w,
                                                        const float* __restrict__ bvec,
                                                        u16* __restrict__ xout,
                                                        int mode) {
  __shared__ float red[4];
  int row = blockIdx.x;
  int b = row / T_SEQ;
  int tid = threadIdx.x;
  float v[5];
  float sum = 0.f;
#pragma unroll
  for (int i = 0; i < 5; ++i) {
    int c = tid + i * 256;
    float val = 0.f;
    if (c < CDIM) {
      if (c < DMODEL) {
        size_t idx = (size_t)row * DMODEL + c;
        if (mode == 1) val = zf[idx];
        else val = zf[idx] + zf2[idx];
      } else {
        val = temb[b * 64 + (c - DMODEL)];
      }
    }
    v[i] = val;
    sum += val;
  }
#pragma unroll
  for (int off = 32; off; off >>= 1) sum += __shfl_xor(sum, off, 64);
  int wv = tid >> 6, ln = tid & 63;
  if (ln == 0) red[wv] = sum;
  __syncthreads();
  float mean = (red[0] + red[1] + red[2] + red[3]) * (1.0f / CDIM);
  __syncthreads();
  float sq = 0.f;
#pragma unroll
  for (int i = 0; i < 5; ++i) {
    int c = tid + i * 256;
    if (c < CDIM) { float d = v[i] - mean; sq += d * d; }
  }
#pragma unroll
  for (int off = 32; off; off >>= 1) sq += __shfl_xor(sq, off, 64);
  if (ln == 0) red[wv] = sq;
  __syncthreads();
  float inv = rsqrtf((red[0] + red[1] + red[2] + red[3]) * (1.0f / CDIM) + 1e-5f);
#pragma unroll
  for (int i = 0; i < 5; ++i) {
    int c = tid + i * 256;
    if (c < CDIM)
      xout[(size_t)row * CDIM + c] = f2b((v[i] - mean) * inv * w[c] + bvec[c]);
  }
}

// ---------------- 256x256 GEMM (kept for fc, where it beats 128^2) -----------
__global__ __launch_bounds__(512, 2) void gemm256_kernel(
    const u16* __restrict__ A, const u16* __restrict__ Bt,
    const float* __restrict__ bias,
    void* __restrict__ c0,
    int M, int N, int K, int k_tiles, int do_gelu) {
  __shared__ u16 As[2][256 * 64];
  __shared__ u16 Bs[2][256 * 64];
  const int tid = threadIdx.x;
  const int wave = tid >> 6, lane = tid & 63;
  const int wr = wave >> 2, wc = wave & 3;
  const int lrow = lane & 15, quad = lane >> 4;

  int nxy = gridDim.x * gridDim.y;
  int bid = blockIdx.y * gridDim.x + blockIdx.x;
  int cpx = nxy >> 3;
  int swz = (bid & 7) * cpx + (bid >> 3);
  int bx = swz % gridDim.x, by = swz / gridDim.x;
  const int m0 = bx * 256, n0 = by * 256;
  const int NT = k_tiles;

  const int sr = tid >> 3;
  const int sc = ((tid & 7) ^ ((tid >> 3) & 7)) * 8;   // elements
  const u16* gA = A + (size_t)(m0 + sr) * K + sc;
  const u16* gB = Bt + (size_t)(n0 + sr) * K + sc;

  f4v acc[8][4] = {};
  b8v bq[2][4];

  auto STAGE_A = [&](int t, int h) {
    const u16* g = gA + (size_t)(h * 128) * K + t * 64;
    u16* l = (u16*)As[t & 1] + h * 8192 + (wave << 9);
    GLL(g, l);
    GLL(g + (size_t)64 * K, l + 4096);
  };
  auto STAGE_B = [&](int t, int h) {
    const u16* g = gB + (size_t)(h * 128) * K + t * 64;
    u16* l = (u16*)Bs[t & 1] + h * 8192 + (wave << 9);
    GLL(g, l);
    GLL(g + (size_t)64 * K, l + 4096);
  };

  STAGE_A(0, 0); STAGE_B(0, 0); STAGE_B(0, 1);
  STAGE_A(0, 1);
  if (NT > 1) { STAGE_A(1, 0); STAGE_B(1, 0); STAGE_B(1, 1); }
  if (NT > 1) asm volatile("s_waitcnt vmcnt(8)" ::: "memory");
  else        asm volatile("s_waitcnt vmcnt(2)" ::: "memory");
  ABAR();

  for (int t = 0; t < NT; ++t) {
    const char* abase = (const char*)As[t & 1];
    const char* bbase = (const char*)Bs[t & 1];
    const int asw = (lrow & 7) << 4;
    b8v af[4];

    // ---- phase 1: (mh=0, kk=0) | stage A-hi(t+1) ----
#pragma unroll
    for (int j = 0; j < 4; ++j)
      af[j] = *(const b8v*)(abase + (j * 32 + wr * 16 + lrow) * 128 + ((quad * 16) ^ asw));
#pragma unroll
    for (int n = 0; n < 4; ++n)
      bq[0][n] = *(const b8v*)(bbase + (wc * 64 + n * 16 + lrow) * 128 + ((quad * 16) ^ asw));
    if (t + 1 < NT) STAGE_A(t + 1, 1);
    __builtin_amdgcn_s_setprio(1);
#pragma unroll
    for (int j = 0; j < 4; ++j)
#pragma unroll
      for (int n = 0; n < 4; ++n)
        acc[j][n] = __builtin_amdgcn_mfma_f32_16x16x32_bf16(bq[0][n], af[j], acc[j][n], 0, 0, 0);
    __builtin_amdgcn_s_setprio(0);
    ABAR();

    // ---- phase 2: (mh=0, kk=1) | W1: drain A-hi(t) for ph3 ----
#pragma unroll
    for (int j = 0; j < 4; ++j)
      af[j] = *(const b8v*)(abase + (j * 32 + wr * 16 + lrow) * 128 + ((64 + quad * 16) ^ asw));
#pragma unroll
    for (int n = 0; n < 4; ++n)
      bq[1][n] = *(const b8v*)(bbase + (wc * 64 + n * 16 + lrow) * 128 + ((64 + quad * 16) ^ asw));
    __builtin_amdgcn_s_setprio(1);
#pragma unroll
    for (int j = 0; j < 4; ++j)
#pragma unroll
      for (int n = 0; n < 4; ++n)
        acc[j][n] = __builtin_amdgcn_mfma_f32_16x16x32_bf16(bq[1][n], af[j], acc[j][n], 0, 0, 0);
    __builtin_amdgcn_s_setprio(0);
    if (t + 1 < NT) asm volatile("s_waitcnt vmcnt(8)" ::: "memory");
    else            asm volatile("s_waitcnt vmcnt(0)" ::: "memory");
    ABAR();

    // ---- phase 3: (mh=1, kk=0) | stage B-lo(t+2), A-lo(t+2) ----
#pragma unroll
    for (int j = 0; j < 4; ++j)
      af[j] = *(const b8v*)(abase + (128 + j * 32 + wr * 16 + lrow) * 128 + ((quad * 16) ^ asw));
    if (t + 2 < NT) { STAGE_B(t + 2, 0); STAGE_A(t + 2, 0); }
    __builtin_amdgcn_s_setprio(1);
#pragma unroll
    for (int j = 0; j < 4; ++j)
#pragma unroll
      for (int n = 0; n < 4; ++n)
        acc[4 + j][n] = __builtin_amdgcn_mfma_f32_16x16x32_bf16(bq[0][n], af[j], acc[4 + j][n], 0, 0, 0);
    __builtin_amdgcn_s_setprio(0);
    ABAR();

    // ---- phase 4: (mh=1, kk=1) | stage B-hi(t+2) | W2: drain tile t+1 ----
#pragma unroll
    for (int j = 0; j < 4; ++j)
      af[j] = *(const b8v*)(abase + (128 + j * 32 + wr * 16 + lrow) * 128 + ((64 + quad * 16) ^ asw));
    if (t + 2 < NT) STAGE_B(t + 2, 1);
    __builtin_amdgcn_s_setprio(1);
#pragma unroll
    for (int j = 0; j < 4; ++j)
#pragma unroll
      for (int n = 0; n < 4; ++n)
        acc[4 + j][n] = __builtin_amdgcn_mfma_f32_16x16x32_bf16(bq[1][n], af[j], acc[4 + j][n], 0, 0, 0);
    __builtin_amdgcn_s_setprio(0);
    if (t + 1 < NT) {
      if (t + 2 < NT) asm volatile("s_waitcnt vmcnt(8)" ::: "memory");
      else            asm volatile("s_waitcnt vmcnt(2)" ::: "memory");
    }
    ABAR();
  }

  u16* Cout = (u16*)c0;
#pragma unroll
  for (int mh = 0; mh < 2; ++mh)
#pragma unroll
    for (int j = 0; j < 4; ++j) {
      int grow = m0 + mh * 128 + j * 32 + wr * 16 + lrow;
      size_t rb = (size_t)grow * N;
#pragma unroll
      for (int n = 0; n < 4; ++n) {
        int gcol = n0 + wc * 64 + n * 16 + quad * 4;
        float4 bv = *(const float4*)(bias + gcol);
        f4v a = acc[mh * 4 + j][n];
        float v0 = a[0] + bv.x, v1 = a[1] + bv.y, v2 = a[2] + bv.z, v3 = a[3] + bv.w;
        if (do_gelu) {
          v0 = gelu_f(v0); v1 = gelu_f(v1); v2 = gelu_f(v2); v3 = gelu_f(v3);
        }
        ushort4 ov;
        ov.x = f2b(v0); ov.y = f2b(v1); ov.z = f2b(v2); ov.w = f2b(v3);
        *(ushort4*)(Cout + rb + gcol) = ov;
      }
    }
}

// ---------------- 128^2 BK=32 GEMM, up-to-4-way split-K ----------------------
// The m97-structure workhorse: 32 KB LDS -> 3-4 blocks/CU when the grid
// provides them; cross-block wave overlap absorbs barrier/vmcnt stalls (m114).
// kz = blockIdx.z selects K-chunk and output buffer; kz==0 adds bias.
// out_f32=0 -> bf16 (+optional gelu); out_f32=1 -> f32 partials.
__global__ __launch_bounds__(256) void gemm128_kernel(const u16* __restrict__ A,
                                                      const u16* __restrict__ Bt,
                                                      const float* __restrict__ bias,
                                                      void* __restrict__ c0,
                                                      void* __restrict__ c1,
                                                      void* __restrict__ c2,
                                                      void* __restrict__ c3,
                                                      int M, int N, int K, int Kc,
                                                      int do_gelu, int out_f32) {
  __shared__ u16 As[2][128 * 32];
  __shared__ u16 Bs[2][128 * 32];
  const int tid = threadIdx.x;
  const int wave = tid >> 6, lane = tid & 63;
  const int wr = wave >> 1, wc = wave & 1;
  const int m0 = blockIdx.x * 128;
  const int n0 = blockIdx.y * 128;
  const int kz = blockIdx.z;
  const int lrow = lane & 15, quad = lane >> 4;
  const int srow = lane >> 2, sseg = lane & 3;

  const u16* gA0 = A  + (size_t)(m0 + wave * 32 + srow) * K + kz * Kc + sseg * 8;
  const u16* gA1 = gA0 + (size_t)16 * K;
  const u16* gB0 = Bt + (size_t)(n0 + wave * 32 + srow) * K + kz * Kc + sseg * 8;
  const u16* gB1 = gB0 + (size_t)16 * K;
  const int la0 = (wave * 32) * 32, la1 = (wave * 32 + 16) * 32;

  f4v acc[4][4] = {};

  GLL(gA0, &As[0][la0]); GLL(gA1, &As[0][la1]);
  GLL(gB0, &Bs[0][la0]); GLL(gB1, &Bs[0][la1]);

  int cur = 0;
  for (int k0 = 0; k0 < Kc; k0 += 32) {
    __syncthreads();
    if (k0 + 32 < Kc) {
      int nxt = cur ^ 1;
      GLL(gA0 + k0 + 32, &As[nxt][la0]); GLL(gA1 + k0 + 32, &As[nxt][la1]);
      GLL(gB0 + k0 + 32, &Bs[nxt][la0]); GLL(gB1 + k0 + 32, &Bs[nxt][la1]);
    }
    b8v af[4], bfr[4];
#pragma unroll
    for (int mi = 0; mi < 4; ++mi)
      af[mi] = *(const b8v*)(&As[cur][(wr * 64 + mi * 16 + lrow) * 32 + quad * 8]);
#pragma unroll
    for (int ni = 0; ni < 4; ++ni)
      bfr[ni] = *(const b8v*)(&Bs[cur][(wc * 64 + ni * 16 + lrow) * 32 + quad * 8]);
#pragma unroll
    for (int mi = 0; mi < 4; ++mi)
#pragma unroll
      for (int ni = 0; ni < 4; ++ni)
        acc[mi][ni] = __builtin_amdgcn_mfma_f32_16x16x32_bf16(bfr[ni], af[mi], acc[mi][ni], 0, 0, 0);
    cur ^= 1;
  }

  void* Cout = (kz == 0) ? c0 : (kz == 1) ? c1 : (kz == 2) ? c2 : c3;
#pragma unroll
  for (int mi = 0; mi < 4; ++mi) {
    int grow = m0 + wr * 64 + mi * 16 + lrow;
    size_t rb = (size_t)grow * N;
#pragma unroll
    for (int ni = 0; ni < 4; ++ni) {
      int gcol = n0 + wc * 64 + ni * 16 + quad * 4;
      float b0 = 0.f, b1 = 0.f, b2 = 0.f, b3 = 0.f;
      if (kz == 0) {
        float4 bv = *(const float4*)(bias + gcol);
        b0 = bv.x; b1 = bv.y; b2 = bv.z; b3 = bv.w;
      }
      float v0 = acc[mi][ni][0] + b0, v1 = acc[mi][ni][1] + b1;
      float v2 = acc[mi][ni][2] + b2, v3 = acc[mi][ni][3] + b3;
      if (do_gelu) {
        v0 = gelu_f(v0); v1 = gelu_f(v1); v2 = gelu_f(v2); v3 = gelu_f(v3);
      }
      if (out_f32) {
        *(float4*)((float*)Cout + rb + gcol) = float4{v0, v1, v2, v3};
      } else {
        ushort4 ov;
        ov.x = f2b(v0); ov.y = f2b(v1); ov.z = f2b(v2); ov.w = f2b(v3);
        *(ushort4*)((u16*)Cout + rb + gcol) = ov;
      }
    }
  }
}

// ---------------- MFMA flash attention (S^T / O^T, QBLK=64, 4 waves) ---------
// K/V double-buffered in LDS with reg-staged async loads (T14), one barrier per
// chunk.  VALU diet: v_perm V-repack, cvt_pk, log2 softmax, diagonal-only mask.
__global__ __launch_bounds__(256) void attn_mfma_kernel(const u16* __restrict__ qkv,
                                                        u16* __restrict__ y) {
  __shared__ u16 Ks[2][64 * 72];        // K row-major  [key][d]
  __shared__ u16 Vts[2][64 * 72];       // V transposed [d][key^swz]
  __shared__ u16 Ps[64 * 72];           // P row-major  [q_local][key]
  const int bh = blockIdx.x;
  const int b = bh >> 4, h = bh & 15;
  const int qt = 31 - (int)blockIdx.y;  // heavy tiles first (LPT)
  const int tid = threadIdx.x, w = tid >> 6, lane = tid & 63;
  const int lrow = lane & 15, quad = lane >> 4;
  const int q0 = qt * 64;
  const int qg = q0 + w * 16 + lrow;

  // staging geometry (256 threads)
  const int kr = tid >> 2, ksg = tid & 3;     // K: row 0..63, 32B seg 0..3
  const int pr = tid >> 3, dsg = tid & 7;     // V: key pair 2pr, d-seg 0..7
  const u16* kbase = qkv + (size_t)(b * T_SEQ + kr) * 3072 + h * 64 + 1024 + ksg * 16;
  const u16* vbase = qkv + (size_t)(b * T_SEQ + 2 * pr) * 3072 + h * 64 + 2048 + dsg * 8;
  const int keyp = (2 * pr) ^ (dsg * 8);
  const int d0 = dsg * 8;

  uint4 krg0, krg1, vrg0, vrg1;
  auto LOADR = [&](int ct) {
    const u16* ksrc = kbase + (size_t)ct * 64 * 3072;
    krg0 = *(const uint4*)(ksrc);
    krg1 = *(const uint4*)(ksrc + 8);
    const u16* vsrc = vbase + (size_t)ct * 64 * 3072;
    vrg0 = *(const uint4*)(vsrc);
    vrg1 = *(const uint4*)(vsrc + 3072);
  };
  auto WRITE = [&](int bi) {
    *(uint4*)(&Ks[bi][kr * 72 + ksg * 16]) = krg0;
    *(uint4*)(&Ks[bi][kr * 72 + ksg * 16 + 8]) = krg1;
    uint32_t aw[4] = {vrg0.x, vrg0.y, vrg0.z, vrg0.w};
    uint32_t bw[4] = {vrg1.x, vrg1.y, vrg1.z, vrg1.w};
#pragma unroll
    for (int m = 0; m < 4; ++m) {
      *(uint32_t*)(&Vts[bi][(d0 + 2 * m) * 72 + keyp]) =
          __builtin_amdgcn_perm(bw[m], aw[m], 0x05040100u);
      *(uint32_t*)(&Vts[bi][(d0 + 2 * m + 1) * 72 + keyp]) =
          __builtin_amdgcn_perm(bw[m], aw[m], 0x07060302u);
    }
  };

  b8v qf[2];
#pragma unroll
  for (int dc = 0; dc < 2; ++dc)
    qf[dc] = *(const b8v*)(qkv + (size_t)(b * T_SEQ + qg) * 3072 + h * 64 + dc * 32 + quad * 8);

  f4v oacc[4] = {};
  float mrun = -__builtin_inff(), lrun = 0.f;
  const float SC = 0.18033688011112042f;   // 0.125 * log2(e)

  LOADR(0);
  WRITE(0);
  __syncthreads();

  const int nch = qt + 1;
  for (int ct = 0; ct < nch; ++ct) {
    const int cur = ct & 1;
    if (ct + 1 < nch) LOADR(ct + 1);      // async: hides under this chunk's compute

    f4v sacc[4] = {};
    __builtin_amdgcn_s_setprio(1);
#pragma unroll
    for (int ks = 0; ks < 4; ++ks)
#pragma unroll
      for (int dc = 0; dc < 2; ++dc) {
        b8v kf = *(const b8v*)(&Ks[cur][(ks * 16 + lrow) * 72 + dc * 32 + quad * 8]);
        sacc[ks] = __builtin_amdgcn_mfma_f32_16x16x32_bf16(kf, qf[dc], sacc[ks], 0, 0, 0);
      }
    __builtin_amdgcn_s_setprio(0);

    if (ct == qt) {                       // mask only on the diagonal chunk
#pragma unroll
      for (int ks = 0; ks < 4; ++ks)
#pragma unroll
        for (int r = 0; r < 4; ++r) {
          int key = ct * 64 + ks * 16 + quad * 4 + r;
          if (key > qg) sacc[ks][r] = -__builtin_inff();
        }
    }

    float rmax = sacc[0][0];
#pragma unroll
    for (int ks = 0; ks < 4; ++ks)
#pragma unroll
      for (int r = 0; r < 4; ++r) rmax = fmaxf(rmax, sacc[ks][r]);
    rmax = fmaxf(rmax, __shfl_xor(rmax, 16, 64));
    rmax = fmaxf(rmax, __shfl_xor(rmax, 32, 64));
    rmax *= SC;                           // into log2 domain
    float mn = fmaxf(mrun, rmax);
    float al = exp2_hw(mrun - mn);
    mrun = mn;
    float psum = 0.f;
#pragma unroll
    for (int ks = 0; ks < 4; ++ks) {
      float p0 = exp2_hw(fmaf(sacc[ks][0], SC, -mn));
      float p1 = exp2_hw(fmaf(sacc[ks][1], SC, -mn));
      float p2 = exp2_hw(fmaf(sacc[ks][2], SC, -mn));
      float p3 = exp2_hw(fmaf(sacc[ks][3], SC, -mn));
      psum += (p0 + p1) + (p2 + p3);
      uint2 pw;
      pw.x = cvt_pk_bf16(p0, p1);
      pw.y = cvt_pk_bf16(p2, p3);
      *(uint2*)(&Ps[(w * 16 + lrow) * 72 + ks * 16 + quad * 4]) = pw;
    }
    psum += __shfl_xor(psum, 16, 64);
    psum += __shfl_xor(psum, 32, 64);
    lrun = lrun * al + psum;
#pragma unroll
    for (int ds = 0; ds < 4; ++ds) oacc[ds] *= al;

    b8v pf[2];
#pragma unroll
    for (int kc = 0; kc < 2; ++kc)
      pf[kc] = *(const b8v*)(&Ps[(w * 16 + lrow) * 72 + kc * 32 + quad * 8]);
    __builtin_amdgcn_s_setprio(1);
#pragma unroll
    for (int ds = 0; ds < 4; ++ds)
#pragma unroll
      for (int kc = 0; kc < 2; ++kc) {
        int d = ds * 16 + lrow;
        int off = (kc * 32 + quad * 8) ^ (((d >> 3) & 7) * 8);
        b8v vfv = *(const b8v*)(&Vts[cur][d * 72 + off]);
        oacc[ds] = __builtin_amdgcn_mfma_f32_16x16x32_bf16(vfv, pf[kc], oacc[ds], 0, 0, 0);
      }
    __builtin_amdgcn_s_setprio(0);

    if (ct + 1 < nch) {
      WRITE((ct + 1) & 1);                // safe: that buffer last read in ct-1,
      __syncthreads();                    // all waves passed ct-1's barrier
    }
  }

  float rinv = 1.0f / lrun;
  u16* yrow = y + (size_t)(b * T_SEQ + qg) * DMODEL + h * 64;
#pragma unroll
  for (int ds = 0; ds < 4; ++ds) {
    uint2 ov;
    ov.x = cvt_pk_bf16(oacc[ds][0] * rinv, oacc[ds][1] * rinv);
    ov.y = cvt_pk_bf16(oacc[ds][2] * rinv, oacc[ds][3] * rinv);
    *(uint2*)(yrow + ds * 16 + quad * 4) = ov;
  }
}

// ----------------------------------------------------------------------------
extern "C" void kernel_launch(void* const* d_in, const int* in_sizes, int n_in,
                              void* d_out, int out_size, void* d_ws, size_t ws_size,
                              hipStream_t stream) {
  const float* z      = (const float*)d_in[0];
  const float* t      = (const float*)d_in[1];
  const float* w_t1   = (const float*)d_in[2];
  const float* b_t1   = (const float*)d_in[3];
  const float* w_t2   = (const float*)d_in[4];
  const float* b_t2   = (const float*)d_in[5];
  const float* ln_a_w = (const float*)d_in[6];
  const float* ln_a_b = (const float*)d_in[7];
  const float* w_attn = (const float*)d_in[8];
  const float* b_attn = (const float*)d_in[9];
  const float* w_proj = (const float*)d_in[10];
  const float* b_proj = (const float*)d_in[11];
  const float* ln_m_w = (const float*)d_in[12];
  const float* ln_m_b = (const float*)d_in[13];
  const float* w_fc   = (const float*)d_in[14];
  const float* b_fc   = (const float*)d_in[15];
  const float* w_fc2  = (const float*)d_in[16];
  const float* b_fc2  = (const float*)d_in[17];

  char* ws = (char*)d_ws;
  float* temb  = (float*)ws;
  u16* wT_attn = (u16*)(ws + 1024);
  u16* wT_proj = wT_attn + (size_t)3072 * 1088;
  u16* wT_fc   = wT_proj + (size_t)1024 * 1024;
  u16* wT_fc2  = wT_fc   + (size_t)4096 * 1088;
  u16* xbuf    = wT_fc2  + (size_t)1024 * 4096;
  u16* big     = xbuf    + (size_t)4096 * 1088;   // qkv, later fc output g
  u16* ybuf    = big     + (size_t)4096 * 4096;
  float* p0    = (float*)(ybuf + (size_t)4096 * 1024);   // f32 partials [4096][1024]
  float* p1    = p0 + (size_t)4096 * 1024;
  // fc2 split-K partials 2/3: d_out itself + the dead wT_attn..wT_fc region
  float* p3    = (float*)wT_attn;

  time_mlp_kernel<<<dim3(1), dim3(128), 0, stream>>>(t, w_t1, b_t1, w_t2, b_t2, temb);

  transpose_kernel<<<dim3(3072 / 32, 1088 / 32), dim3(256), 0, stream>>>(w_attn, wT_attn, 1088, 3072);
  transpose_kernel<<<dim3(1024 / 32, 1024 / 32), dim3(256), 0, stream>>>(w_proj, wT_proj, 1024, 1024);
  transpose_kernel<<<dim3(4096 / 32, 1088 / 32), dim3(256), 0, stream>>>(w_fc, wT_fc, 1088, 4096);
  transpose_kernel<<<dim3(1024 / 32, 4096 / 32), dim3(256), 0, stream>>>(w_fc2, wT_fc2, 4096, 1024);

  ln_concat_kernel<<<dim3(MROWS), dim3(256), 0, stream>>>(
      z, (const float*)nullptr, temb, ln_a_w, ln_a_b, xbuf, 1);

  // qkv: 128^2 (768 blocks = 3/CU), direct bf16 out
  gemm128_kernel<<<dim3(MROWS / 128, 3072 / 128, 1), dim3(256), 0, stream>>>(
      xbuf, wT_attn, b_attn, big, nullptr, nullptr, nullptr,
      MROWS, 3072, 1088, 1088, 0, 0);

  // attn: QBLK=64, 256 thr, grid 32 bh x 32 q-tiles (1024 blocks)
  attn_mfma_kernel<<<dim3(32, 32), dim3(256), 0, stream>>>(big, ybuf);

  // proj: 128^2 split-K=2 into p0/p1 (512 blocks)
  gemm128_kernel<<<dim3(MROWS / 128, 1024 / 128, 2), dim3(256), 0, stream>>>(
      ybuf, wT_proj, b_proj, p0, p1, nullptr, nullptr,
      MROWS, 1024, 1024, 512, 0, 1);

  // ln_m reads h = p0 + p1
  ln_concat_kernel<<<dim3(MROWS), dim3(256), 0, stream>>>(
      p0, p1, temb, ln_m_w, ln_m_b, xbuf, 2);

  // fc: 256^2 + fused GELU, grid 16x16 (256 blocks) — 256^2 beats 128^2 here
  gemm256_kernel<<<dim3(16, 16, 1), dim3(512), 0, stream>>>(
      xbuf, wT_fc, b_fc, big, MROWS, 4096, 1088, 17, 1);

  // fc2: 128^2 split-K=4 (grid 32x8x4 = 1024 blocks = 4/CU), f32 partials
  gemm128_kernel<<<dim3(MROWS / 128, 1024 / 128, 4), dim3(256), 0, stream>>>(
      big, wT_fc2, b_fc2, p0, p1, d_out, p3,
      MROWS, 1024, 4096, 1024, 0, 1);

  // combine: d_out = p0 + p1 + d_out(p2) + p3
  add4_kernel<<<dim3(MROWS * 1024 / 4 / 256), dim3(256), 0, stream>>>(
      (const float4*)p0, (const float4*)p1, (const float4*)d_out, (const float4*)p3,
      (float4*)d_out, MROWS * 1024 / 4);
}

// Round 13
// 373.859 us; speedup vs baseline: 1.0406x; 1.0406x over previous
//
#include <hip/hip_runtime.h>
#include <stdint.h>
#include <math.h>

#define T_SEQ 2048
#define NHEAD 16
#define HD 64
#define DMODEL 1024
#define CDIM 1088
#define MROWS 4096

typedef uint16_t u16;
typedef __bf16 b8v __attribute__((ext_vector_type(8)));
typedef float f4v __attribute__((ext_vector_type(4)));

typedef __attribute__((address_space(3))) void lds_void;
typedef const __attribute__((address_space(1))) void glb_void;

#define GLL(g, l) __builtin_amdgcn_global_load_lds((glb_void*)(g), (lds_void*)(l), 16, 0, 0)
// raw HW barrier (opaque to compiler reordering via "memory" clobber)
#define ABAR() asm volatile("s_barrier" ::: "memory")

__device__ __forceinline__ u16 f2b(float f) {
  union { float f; uint32_t i; } c; c.f = f;
  uint32_t x = c.i;
  return (u16)((x + 0x7fffu + ((x >> 16) & 1u)) >> 16);
}
// packed f32x2 -> bf16x2 (RNE) in one instruction; no builtin on gfx950 (m240)
__device__ __forceinline__ uint32_t cvt_pk_bf16(float lo, float hi) {
  uint32_t r;
  asm("v_cvt_pk_bf16_f32 %0, %1, %2" : "=v"(r) : "v"(lo), "v"(hi));
  return r;
}
// hardware 2^x (v_exp_f32); avoids glibc __exp2f macro collision
__device__ __forceinline__ float exp2_hw(float x) {
  return __builtin_amdgcn_exp2f(x);
}
// Fast exact-GELU: erf via Abramowitz-Stegun 7.1.26 (max abs err 1.5e-7).
__device__ __forceinline__ float gelu_f(float x) {
  float ax = fabsf(x);
  float xs = ax * 0.70710678118654752f;
  float t = __frcp_rn(1.0f + 0.3275911f * xs);
  float poly = ((((1.061405429f * t - 1.453152027f) * t + 1.421413741f) * t
                 - 0.284496736f) * t + 0.254829592f) * t;
  float e = __expf(-xs * xs);
  float er = 1.0f - poly * e;
  er = copysignf(er, x);
  return 0.5f * x * (1.0f + er);
}

// ---------------- all 4 weight transposes in ONE kernel ----------------------
// f32[R][C] -> bf16[C][R].  Flat grid, range-decoded:
//  t0 w_attn 1088x3072 (96x34=3264) | t1 w_proj 1024x1024 (32x32=1024)
//  t2 w_fc   1088x4096 (128x34=4352)| t3 w_fc2  4096x1024 (32x128=4096)
__global__ __launch_bounds__(256) void transpose_all_kernel(
    const float* __restrict__ s0, u16* __restrict__ d0,
    const float* __restrict__ s1, u16* __restrict__ d1,
    const float* __restrict__ s2, u16* __restrict__ d2,
    const float* __restrict__ s3, u16* __restrict__ d3) {
  __shared__ u16 tile[32][33];
  int bid = blockIdx.x;
  const float* src; u16* dst; int R, C, nbx;
  if (bid < 3264)      { src = s0; dst = d0; R = 1088; C = 3072; nbx = 96; }
  else if (bid < 4288) { src = s1; dst = d1; R = 1024; C = 1024; nbx = 32; bid -= 3264; }
  else if (bid < 8640) { src = s2; dst = d2; R = 1088; C = 4096; nbx = 128; bid -= 4288; }
  else                 { src = s3; dst = d3; R = 4096; C = 1024; nbx = 32; bid -= 8640; }
  int c0 = (bid % nbx) * 32, r0 = (bid / nbx) * 32;
  int tx = threadIdx.x & 31, ty = threadIdx.x >> 5;   // ty 0..7
#pragma unroll
  for (int i = 0; i < 4; ++i) {
    int r = ty + i * 8;
    tile[r][tx] = f2b(src[(size_t)(r0 + r) * C + c0 + tx]);
  }
  __syncthreads();
#pragma unroll
  for (int i = 0; i < 4; ++i) {
    int c = ty + i * 8;
    dst[(size_t)(c0 + c) * R + r0 + tx] = tile[tx][c];
  }
}

// ---------------- add four f32 buffers -> f32 out (fc2 split-K reduce) -------
__global__ __launch_bounds__(256) void add4_kernel(const float4* __restrict__ a,
                                                   const float4* __restrict__ b,
                                                   const float4* __restrict__ c,
                                                   const float4* __restrict__ d,
                                                   float4* __restrict__ o, int n4) {
  int i = blockIdx.x * 256 + threadIdx.x;
  if (i < n4) {
    float4 x = a[i], y = b[i], z = c[i], w = d[i];
    o[i] = float4{x.x + y.x + z.x + w.x, x.y + y.y + z.y + w.y,
                  x.z + y.z + z.z + w.z, x.w + y.w + z.w + w.w};
  }
}

// ---------------- fused time-MLP + concat + LayerNorm -> bf16 ----------------
// temb (64-elem time embedding) is recomputed IN-BLOCK (64x64 matvec, weights
// L2-resident) -- removes the separate time_mlp kernel and its serialization.
// mode 1: z from zf (f32); mode 2: z = zf + zf2 (f32)
__global__ __launch_bounds__(256) void ln_concat_kernel(const float* __restrict__ zf,
                                                        const float* __restrict__ zf2,
                                                        const float* __restrict__ t,
                                                        const float* __restrict__ w1,
                                                        const float* __restrict__ b1,
                                                        const float* __restrict__ w2,
                                                        const float* __restrict__ b2,
                                                        const float* __restrict__ w,
                                                        const float* __restrict__ bvec,
                                                        u16* __restrict__ xout,
                                                        int mode) {
  __shared__ float red[4];
  __shared__ float h1[64];
  __shared__ float temb_s[64];
  int row = blockIdx.x;
  int b = row / T_SEQ;
  int tid = threadIdx.x;

  if (tid < 64) h1[tid] = gelu_f(t[b] * w1[tid] + b1[tid]);
  __syncthreads();
  if (tid < 64) {
    float acc = b2[tid];
#pragma unroll 8
    for (int k = 0; k < 64; ++k) acc += h1[k] * w2[k * 64 + tid];
    temb_s[tid] = acc;
  }
  __syncthreads();

  float v[5];
  float sum = 0.f;
#pragma unroll
  for (int i = 0; i < 5; ++i) {
    int c = tid + i * 256;
    float val = 0.f;
    if (c < CDIM) {
      if (c < DMODEL) {
        size_t idx = (size_t)row * DMODEL + c;
        if (mode == 1) val = zf[idx];
        else val = zf[idx] + zf2[idx];
      } else {
        val = temb_s[c - DMODEL];
      }
    }
    v[i] = val;
    sum += val;
  }
#pragma unroll
  for (int off = 32; off; off >>= 1) sum += __shfl_xor(sum, off, 64);
  int wv = tid >> 6, ln = tid & 63;
  if (ln == 0) red[wv] = sum;
  __syncthreads();
  float mean = (red[0] + red[1] + red[2] + red[3]) * (1.0f / CDIM);
  __syncthreads();
  float sq = 0.f;
#pragma unroll
  for (int i = 0; i < 5; ++i) {
    int c = tid + i * 256;
    if (c < CDIM) { float d = v[i] - mean; sq += d * d; }
  }
#pragma unroll
  for (int off = 32; off; off >>= 1) sq += __shfl_xor(sq, off, 64);
  if (ln == 0) red[wv] = sq;
  __syncthreads();
  float inv = rsqrtf((red[0] + red[1] + red[2] + red[3]) * (1.0f / CDIM) + 1e-5f);
#pragma unroll
  for (int i = 0; i < 5; ++i) {
    int c = tid + i * 256;
    if (c < CDIM)
      xout[(size_t)row * CDIM + c] = f2b((v[i] - mean) * inv * w[c] + bvec[c]);
  }
}

// ---------------- 256x256 GEMM: 4 phases/K-tile, one barrier per phase -------
// (round-10 body: best measured 56.7-56.9 us, VGPR 100.)  T2 swizzle, counted
// vmcnt(8) ledger (FIFO-verified), T5 setprio, XCD-swizzled grid.
__global__ __launch_bounds__(512, 2) void gemm256_kernel(
    const u16* __restrict__ A, const u16* __restrict__ Bt,
    const float* __restrict__ bias,
    void* __restrict__ c0, void* __restrict__ c1,
    void* __restrict__ c2, void* __restrict__ c3,
    int M, int N, int K, int k_tiles, int do_gelu, int out_f32) {
  __shared__ u16 As[2][256 * 64];
  __shared__ u16 Bs[2][256 * 64];
  const int tid = threadIdx.x;
  const int wave = tid >> 6, lane = tid & 63;
  const int wr = wave >> 2, wc = wave & 3;
  const int lrow = lane & 15, quad = lane >> 4;

  int nxy = gridDim.x * gridDim.y;
  int bid = blockIdx.y * gridDim.x + blockIdx.x;
  int cpx = nxy >> 3;
  int swz = (bid & 7) * cpx + (bid >> 3);
  int bx = swz % gridDim.x, by = swz / gridDim.x;
  const int m0 = bx * 256, n0 = by * 256;
  const int kz = blockIdx.z;
  const int kb = kz * k_tiles * 64;
  const int NT = k_tiles;

  const int sr = tid >> 3;
  const int sc = ((tid & 7) ^ ((tid >> 3) & 7)) * 8;   // elements
  const u16* gA = A + (size_t)(m0 + sr) * K + kb + sc;
  const u16* gB = Bt + (size_t)(n0 + sr) * K + kb + sc;

  f4v acc[8][4] = {};
  b8v bq[2][4];

  auto STAGE_A = [&](int t, int h) {
    const u16* g = gA + (size_t)(h * 128) * K + t * 64;
    u16* l = (u16*)As[t & 1] + h * 8192 + (wave << 9);
    GLL(g, l);
    GLL(g + (size_t)64 * K, l + 4096);
  };
  auto STAGE_B = [&](int t, int h) {
    const u16* g = gB + (size_t)(h * 128) * K + t * 64;
    u16* l = (u16*)Bs[t & 1] + h * 8192 + (wave << 9);
    GLL(g, l);
    GLL(g + (size_t)64 * K, l + 4096);
  };

  STAGE_A(0, 0); STAGE_B(0, 0); STAGE_B(0, 1);
  STAGE_A(0, 1);
  if (NT > 1) { STAGE_A(1, 0); STAGE_B(1, 0); STAGE_B(1, 1); }
  if (NT > 1) asm volatile("s_waitcnt vmcnt(8)" ::: "memory");
  else        asm volatile("s_waitcnt vmcnt(2)" ::: "memory");
  ABAR();

  for (int t = 0; t < NT; ++t) {
    const char* abase = (const char*)As[t & 1];
    const char* bbase = (const char*)Bs[t & 1];
    const int asw = (lrow & 7) << 4;
    b8v af[4];

    // ---- phase 1: (mh=0, kk=0) | stage A-hi(t+1) ----
#pragma unroll
    for (int j = 0; j < 4; ++j)
      af[j] = *(const b8v*)(abase + (j * 32 + wr * 16 + lrow) * 128 + ((quad * 16) ^ asw));
#pragma unroll
    for (int n = 0; n < 4; ++n)
      bq[0][n] = *(const b8v*)(bbase + (wc * 64 + n * 16 + lrow) * 128 + ((quad * 16) ^ asw));
    if (t + 1 < NT) STAGE_A(t + 1, 1);
    __builtin_amdgcn_s_setprio(1);
#pragma unroll
    for (int j = 0; j < 4; ++j)
#pragma unroll
      for (int n = 0; n < 4; ++n)
        acc[j][n] = __builtin_amdgcn_mfma_f32_16x16x32_bf16(bq[0][n], af[j], acc[j][n], 0, 0, 0);
    __builtin_amdgcn_s_setprio(0);
    ABAR();

    // ---- phase 2: (mh=0, kk=1) | W1: drain A-hi(t) for ph3 ----
#pragma unroll
    for (int j = 0; j < 4; ++j)
      af[j] = *(const b8v*)(abase + (j * 32 + wr * 16 + lrow) * 128 + ((64 + quad * 16) ^ asw));
#pragma unroll
    for (int n = 0; n < 4; ++n)
      bq[1][n] = *(const b8v*)(bbase + (wc * 64 + n * 16 + lrow) * 128 + ((64 + quad * 16) ^ asw));
    __builtin_amdgcn_s_setprio(1);
#pragma unroll
    for (int j = 0; j < 4; ++j)
#pragma unroll
      for (int n = 0; n < 4; ++n)
        acc[j][n] = __builtin_amdgcn_mfma_f32_16x16x32_bf16(bq[1][n], af[j], acc[j][n], 0, 0, 0);
    __builtin_amdgcn_s_setprio(0);
    if (t + 1 < NT) asm volatile("s_waitcnt vmcnt(8)" ::: "memory");
    else            asm volatile("s_waitcnt vmcnt(0)" ::: "memory");
    ABAR();

    // ---- phase 3: (mh=1, kk=0) | stage B-lo(t+2), A-lo(t+2) ----
#pragma unroll
    for (int j = 0; j < 4; ++j)
      af[j] = *(const b8v*)(abase + (128 + j * 32 + wr * 16 + lrow) * 128 + ((quad * 16) ^ asw));
    if (t + 2 < NT) { STAGE_B(t + 2, 0); STAGE_A(t + 2, 0); }
    __builtin_amdgcn_s_setprio(1);
#pragma unroll
    for (int j = 0; j < 4; ++j)
#pragma unroll
      for (int n = 0; n < 4; ++n)
        acc[4 + j][n] = __builtin_amdgcn_mfma_f32_16x16x32_bf16(bq[0][n], af[j], acc[4 + j][n], 0, 0, 0);
    __builtin_amdgcn_s_setprio(0);
    ABAR();

    // ---- phase 4: (mh=1, kk=1) | stage B-hi(t+2) | W2: drain tile t+1 ----
#pragma unroll
    for (int j = 0; j < 4; ++j)
      af[j] = *(const b8v*)(abase + (128 + j * 32 + wr * 16 + lrow) * 128 + ((64 + quad * 16) ^ asw));
    if (t + 2 < NT) STAGE_B(t + 2, 1);
    __builtin_amdgcn_s_setprio(1);
#pragma unroll
    for (int j = 0; j < 4; ++j)
#pragma unroll
      for (int n = 0; n < 4; ++n)
        acc[4 + j][n] = __builtin_amdgcn_mfma_f32_16x16x32_bf16(bq[1][n], af[j], acc[4 + j][n], 0, 0, 0);
    __builtin_amdgcn_s_setprio(0);
    if (t + 1 < NT) {
      if (t + 2 < NT) asm volatile("s_waitcnt vmcnt(8)" ::: "memory");
      else            asm volatile("s_waitcnt vmcnt(2)" ::: "memory");
    }
    ABAR();
  }

  void* Cout = (kz == 0) ? c0 : (kz == 1) ? c1 : (kz == 2) ? c2 : c3;
#pragma unroll
  for (int mh = 0; mh < 2; ++mh)
#pragma unroll
    for (int j = 0; j < 4; ++j) {
      int grow = m0 + mh * 128 + j * 32 + wr * 16 + lrow;
      size_t rb = (size_t)grow * N;
#pragma unroll
      for (int n = 0; n < 4; ++n) {
        int gcol = n0 + wc * 64 + n * 16 + quad * 4;
        float b0 = 0.f, b1 = 0.f, b2 = 0.f, b3 = 0.f;
        if (kz == 0) {
          float4 bv = *(const float4*)(bias + gcol);
          b0 = bv.x; b1 = bv.y; b2 = bv.z; b3 = bv.w;
        }
        f4v a = acc[mh * 4 + j][n];
        float v0 = a[0] + b0, v1 = a[1] + b1, v2 = a[2] + b2, v3 = a[3] + b3;
        if (do_gelu) {
          v0 = gelu_f(v0); v1 = gelu_f(v1); v2 = gelu_f(v2); v3 = gelu_f(v3);
        }
        if (out_f32) {
          *(float4*)((float*)Cout + rb + gcol) = float4{v0, v1, v2, v3};
        } else {
          ushort4 ov;
          ov.x = f2b(v0); ov.y = f2b(v1); ov.z = f2b(v2); ov.w = f2b(v3);
          *(ushort4*)((u16*)Cout + rb + gcol) = ov;
        }
      }
    }
}

// ---------------- 128^2 BK=32 GEMM, split-K (kept for proj) ------------------
__global__ __launch_bounds__(256) void gemm128_kernel(const u16* __restrict__ A,
                                                      const u16* __restrict__ Bt,
                                                      const float* __restrict__ bias,
                                                      void* __restrict__ c0,
                                                      void* __restrict__ c1,
                                                      int M, int N, int K, int Kc,
                                                      int out_f32) {
  __shared__ u16 As[2][128 * 32];
  __shared__ u16 Bs[2][128 * 32];
  const int tid = threadIdx.x;
  const int wave = tid >> 6, lane = tid & 63;
  const int wr = wave >> 1, wc = wave & 1;
  const int m0 = blockIdx.x * 128;
  const int n0 = blockIdx.y * 128;
  const int kz = blockIdx.z;
  const int lrow = lane & 15, quad = lane >> 4;
  const int srow = lane >> 2, sseg = lane & 3;

  const u16* gA0 = A  + (size_t)(m0 + wave * 32 + srow) * K + kz * Kc + sseg * 8;
  const u16* gA1 = gA0 + (size_t)16 * K;
  const u16* gB0 = Bt + (size_t)(n0 + wave * 32 + srow) * K + kz * Kc + sseg * 8;
  const u16* gB1 = gB0 + (size_t)16 * K;
  const int la0 = (wave * 32) * 32, la1 = (wave * 32 + 16) * 32;

  f4v acc[4][4] = {};

  GLL(gA0, &As[0][la0]); GLL(gA1, &As[0][la1]);
  GLL(gB0, &Bs[0][la0]); GLL(gB1, &Bs[0][la1]);

  int cur = 0;
  for (int k0 = 0; k0 < Kc; k0 += 32) {
    __syncthreads();
    if (k0 + 32 < Kc) {
      int nxt = cur ^ 1;
      GLL(gA0 + k0 + 32, &As[nxt][la0]); GLL(gA1 + k0 + 32, &As[nxt][la1]);
      GLL(gB0 + k0 + 32, &Bs[nxt][la0]); GLL(gB1 + k0 + 32, &Bs[nxt][la1]);
    }
    b8v af[4], bfr[4];
#pragma unroll
    for (int mi = 0; mi < 4; ++mi)
      af[mi] = *(const b8v*)(&As[cur][(wr * 64 + mi * 16 + lrow) * 32 + quad * 8]);
#pragma unroll
    for (int ni = 0; ni < 4; ++ni)
      bfr[ni] = *(const b8v*)(&Bs[cur][(wc * 64 + ni * 16 + lrow) * 32 + quad * 8]);
#pragma unroll
    for (int mi = 0; mi < 4; ++mi)
#pragma unroll
      for (int ni = 0; ni < 4; ++ni)
        acc[mi][ni] = __builtin_amdgcn_mfma_f32_16x16x32_bf16(bfr[ni], af[mi], acc[mi][ni], 0, 0, 0);
    cur ^= 1;
  }

  void* Cout = kz ? c1 : c0;
#pragma unroll
  for (int mi = 0; mi < 4; ++mi) {
    int grow = m0 + wr * 64 + mi * 16 + lrow;
    size_t rb = (size_t)grow * N;
#pragma unroll
    for (int ni = 0; ni < 4; ++ni) {
      int gcol = n0 + wc * 64 + ni * 16 + quad * 4;
      float b0 = 0.f, b1 = 0.f, b2 = 0.f, b3 = 0.f;
      if (kz == 0) {
        float4 bv = *(const float4*)(bias + gcol);
        b0 = bv.x; b1 = bv.y; b2 = bv.z; b3 = bv.w;
      }
      float v0 = acc[mi][ni][0] + b0, v1 = acc[mi][ni][1] + b1;
      float v2 = acc[mi][ni][2] + b2, v3 = acc[mi][ni][3] + b3;
      if (out_f32) {
        *(float4*)((float*)Cout + rb + gcol) = float4{v0, v1, v2, v3};
      } else {
        ushort4 ov;
        ov.x = f2b(v0); ov.y = f2b(v1); ov.z = f2b(v2); ov.w = f2b(v3);
        *(ushort4*)((u16*)Cout + rb + gcol) = ov;
      }
    }
  }
}

// ---------------- MFMA flash attention (S^T / O^T, QBLK=64, 4 waves) ---------
// K/V double-buffered in LDS with reg-staged async loads (T14), one barrier per
// chunk.  VALU diet: v_perm V-repack, cvt_pk, log2 softmax, diagonal-only mask.
__global__ __launch_bounds__(256) void attn_mfma_kernel(const u16* __restrict__ qkv,
                                                        u16* __restrict__ y) {
  __shared__ u16 Ks[2][64 * 72];        // K row-major  [key][d]
  __shared__ u16 Vts[2][64 * 72];       // V transposed [d][key^swz]
  __shared__ u16 Ps[64 * 72];           // P row-major  [q_local][key]
  const int bh = blockIdx.x;
  const int b = bh >> 4, h = bh & 15;
  const int qt = 31 - (int)blockIdx.y;  // heavy tiles first (LPT)
  const int tid = threadIdx.x, w = tid >> 6, lane = tid & 63;
  const int lrow = lane & 15, quad = lane >> 4;
  const int q0 = qt * 64;
  const int qg = q0 + w * 16 + lrow;

  // staging geometry (256 threads)
  const int kr = tid >> 2, ksg = tid & 3;     // K: row 0..63, 32B seg 0..3
  const int pr = tid >> 3, dsg = tid & 7;     // V: key pair 2pr, d-seg 0..7
  const u16* kbase = qkv + (size_t)(b * T_SEQ + kr) * 3072 + h * 64 + 1024 + ksg * 16;
  const u16* vbase = qkv + (size_t)(b * T_SEQ + 2 * pr) * 3072 + h * 64 + 2048 + dsg * 8;
  const int keyp = (2 * pr) ^ (dsg * 8);
  const int d0 = dsg * 8;

  uint4 krg0, krg1, vrg0, vrg1;
  auto LOADR = [&](int ct) {
    const u16* ksrc = kbase + (size_t)ct * 64 * 3072;
    krg0 = *(const uint4*)(ksrc);
    krg1 = *(const uint4*)(ksrc + 8);
    const u16* vsrc = vbase + (size_t)ct * 64 * 3072;
    vrg0 = *(const uint4*)(vsrc);
    vrg1 = *(const uint4*)(vsrc + 3072);
  };
  auto WRITE = [&](int bi) {
    *(uint4*)(&Ks[bi][kr * 72 + ksg * 16]) = krg0;
    *(uint4*)(&Ks[bi][kr * 72 + ksg * 16 + 8]) = krg1;
    uint32_t aw[4] = {vrg0.x, vrg0.y, vrg0.z, vrg0.w};
    uint32_t bw[4] = {vrg1.x, vrg1.y, vrg1.z, vrg1.w};
#pragma unroll
    for (int m = 0; m < 4; ++m) {
      *(uint32_t*)(&Vts[bi][(d0 + 2 * m) * 72 + keyp]) =
          __builtin_amdgcn_perm(bw[m], aw[m], 0x05040100u);
      *(uint32_t*)(&Vts[bi][(d0 + 2 * m + 1) * 72 + keyp]) =
          __builtin_amdgcn_perm(bw[m], aw[m], 0x07060302u);
    }
  };

  b8v qf[2];
#pragma unroll
  for (int dc = 0; dc < 2; ++dc)
    qf[dc] = *(const b8v*)(qkv + (size_t)(b * T_SEQ + qg) * 3072 + h * 64 + dc * 32 + quad * 8);

  f4v oacc[4] = {};
  float mrun = -__builtin_inff(), lrun = 0.f;
  const float SC = 0.18033688011112042f;   // 0.125 * log2(e)

  LOADR(0);
  WRITE(0);
  __syncthreads();

  const int nch = qt + 1;
  for (int ct = 0; ct < nch; ++ct) {
    const int cur = ct & 1;
    if (ct + 1 < nch) LOADR(ct + 1);      // async: hides under this chunk's compute

    f4v sacc[4] = {};
    __builtin_amdgcn_s_setprio(1);
#pragma unroll
    for (int ks = 0; ks < 4; ++ks)
#pragma unroll
      for (int dc = 0; dc < 2; ++dc) {
        b8v kf = *(const b8v*)(&Ks[cur][(ks * 16 + lrow) * 72 + dc * 32 + quad * 8]);
        sacc[ks] = __builtin_amdgcn_mfma_f32_16x16x32_bf16(kf, qf[dc], sacc[ks], 0, 0, 0);
      }
    __builtin_amdgcn_s_setprio(0);

    if (ct == qt) {                       // mask only on the diagonal chunk
#pragma unroll
      for (int ks = 0; ks < 4; ++ks)
#pragma unroll
        for (int r = 0; r < 4; ++r) {
          int key = ct * 64 + ks * 16 + quad * 4 + r;
          if (key > qg) sacc[ks][r] = -__builtin_inff();
        }
    }

    float rmax = sacc[0][0];
#pragma unroll
    for (int ks = 0; ks < 4; ++ks)
#pragma unroll
      for (int r = 0; r < 4; ++r) rmax = fmaxf(rmax, sacc[ks][r]);
    rmax = fmaxf(rmax, __shfl_xor(rmax, 16, 64));
    rmax = fmaxf(rmax, __shfl_xor(rmax, 32, 64));
    rmax *= SC;                           // into log2 domain
    float mn = fmaxf(mrun, rmax);
    float al = exp2_hw(mrun - mn);
    mrun = mn;
    float psum = 0.f;
#pragma unroll
    for (int ks = 0; ks < 4; ++ks) {
      float p0 = exp2_hw(fmaf(sacc[ks][0], SC, -mn));
      float p1 = exp2_hw(fmaf(sacc[ks][1], SC, -mn));
      float p2 = exp2_hw(fmaf(sacc[ks][2], SC, -mn));
      float p3 = exp2_hw(fmaf(sacc[ks][3], SC, -mn));
      psum += (p0 + p1) + (p2 + p3);
      uint2 pw;
      pw.x = cvt_pk_bf16(p0, p1);
      pw.y = cvt_pk_bf16(p2, p3);
      *(uint2*)(&Ps[(w * 16 + lrow) * 72 + ks * 16 + quad * 4]) = pw;
    }
    psum += __shfl_xor(psum, 16, 64);
    psum += __shfl_xor(psum, 32, 64);
    lrun = lrun * al + psum;
#pragma unroll
    for (int ds = 0; ds < 4; ++ds) oacc[ds] *= al;

    b8v pf[2];
#pragma unroll
    for (int kc = 0; kc < 2; ++kc)
      pf[kc] = *(const b8v*)(&Ps[(w * 16 + lrow) * 72 + kc * 32 + quad * 8]);
    __builtin_amdgcn_s_setprio(1);
#pragma unroll
    for (int ds = 0; ds < 4; ++ds)
#pragma unroll
      for (int kc = 0; kc < 2; ++kc) {
        int d = ds * 16 + lrow;
        int off = (kc * 32 + quad * 8) ^ (((d >> 3) & 7) * 8);
        b8v vfv = *(const b8v*)(&Vts[cur][d * 72 + off]);
        oacc[ds] = __builtin_amdgcn_mfma_f32_16x16x32_bf16(vfv, pf[kc], oacc[ds], 0, 0, 0);
      }
    __builtin_amdgcn_s_setprio(0);

    if (ct + 1 < nch) {
      WRITE((ct + 1) & 1);                // safe: that buffer last read in ct-1,
      __syncthreads();                    // all waves passed ct-1's barrier
    }
  }

  float rinv = 1.0f / lrun;
  u16* yrow = y + (size_t)(b * T_SEQ + qg) * DMODEL + h * 64;
#pragma unroll
  for (int ds = 0; ds < 4; ++ds) {
    uint2 ov;
    ov.x = cvt_pk_bf16(oacc[ds][0] * rinv, oacc[ds][1] * rinv);
    ov.y = cvt_pk_bf16(oacc[ds][2] * rinv, oacc[ds][3] * rinv);
    *(uint2*)(yrow + ds * 16 + quad * 4) = ov;
  }
}

// ----------------------------------------------------------------------------
extern "C" void kernel_launch(void* const* d_in, const int* in_sizes, int n_in,
                              void* d_out, int out_size, void* d_ws, size_t ws_size,
                              hipStream_t stream) {
  const float* z      = (const float*)d_in[0];
  const float* t      = (const float*)d_in[1];
  const float* w_t1   = (const float*)d_in[2];
  const float* b_t1   = (const float*)d_in[3];
  const float* w_t2   = (const float*)d_in[4];
  const float* b_t2   = (const float*)d_in[5];
  const float* ln_a_w = (const float*)d_in[6];
  const float* ln_a_b = (const float*)d_in[7];
  const float* w_attn = (const float*)d_in[8];
  const float* b_attn = (const float*)d_in[9];
  const float* w_proj = (const float*)d_in[10];
  const float* b_proj = (const float*)d_in[11];
  const float* ln_m_w = (const float*)d_in[12];
  const float* ln_m_b = (const float*)d_in[13];
  const float* w_fc   = (const float*)d_in[14];
  const float* b_fc   = (const float*)d_in[15];
  const float* w_fc2  = (const float*)d_in[16];
  const float* b_fc2  = (const float*)d_in[17];

  char* ws = (char*)d_ws;
  u16* wT_attn = (u16*)(ws + 1024);
  u16* wT_proj = wT_attn + (size_t)3072 * 1088;
  u16* wT_fc   = wT_proj + (size_t)1024 * 1024;
  u16* wT_fc2  = wT_fc   + (size_t)4096 * 1088;
  u16* xbuf    = wT_fc2  + (size_t)1024 * 4096;
  u16* big     = xbuf    + (size_t)4096 * 1088;   // qkv, later fc output g
  u16* ybuf    = big     + (size_t)4096 * 4096;
  float* p0    = (float*)(ybuf + (size_t)4096 * 1024);   // f32 partials [4096][1024]
  float* p1    = p0 + (size_t)4096 * 1024;
  // fc2 split-K partials 2/3: d_out itself + the dead wT_attn..wT_fc region
  float* p3    = (float*)wT_attn;

  // all 4 weight transposes in one launch (12736 blocks)
  transpose_all_kernel<<<dim3(12736), dim3(256), 0, stream>>>(
      w_attn, wT_attn, w_proj, wT_proj, w_fc, wT_fc, w_fc2, wT_fc2);

  // ln_a (time-MLP fused in-block)
  ln_concat_kernel<<<dim3(MROWS), dim3(256), 0, stream>>>(
      z, (const float*)nullptr, t, w_t1, b_t1, w_t2, b_t2,
      ln_a_w, ln_a_b, xbuf, 1);

  // qkv: 256^2, grid 16x12 (192 blocks), K=1088 -> 17 K-tiles
  gemm256_kernel<<<dim3(16, 12, 1), dim3(512), 0, stream>>>(
      xbuf, wT_attn, b_attn, big, nullptr, nullptr, nullptr,
      MROWS, 3072, 1088, 17, 0, 0);

  // attn: QBLK=64, 256 thr, grid 32 bh x 32 q-tiles (1024 blocks)
  attn_mfma_kernel<<<dim3(32, 32), dim3(256), 0, stream>>>(big, ybuf);

  // proj: 128^2 split-K=2 into p0/p1 (512 blocks)
  gemm128_kernel<<<dim3(MROWS / 128, 1024 / 128, 2), dim3(256), 0, stream>>>(
      ybuf, wT_proj, b_proj, p0, p1, MROWS, 1024, 1024, 512, 1);

  // ln_m reads h = p0 + p1 (time-MLP fused in-block)
  ln_concat_kernel<<<dim3(MROWS), dim3(256), 0, stream>>>(
      p0, p1, t, w_t1, b_t1, w_t2, b_t2,
      ln_m_w, ln_m_b, xbuf, 2);

  // fc: 256^2 + fused GELU, grid 16x16 (256 blocks)
  gemm256_kernel<<<dim3(16, 16, 1), dim3(512), 0, stream>>>(
      xbuf, wT_fc, b_fc, big, nullptr, nullptr, nullptr,
      MROWS, 4096, 1088, 17, 1, 0);

  // fc2: 256^2 split-K=4 (grid 16x4x4 = 256 blocks), f32 partials
  gemm256_kernel<<<dim3(16, 4, 4), dim3(512), 0, stream>>>(
      big, wT_fc2, b_fc2, p0, p1, d_out, p3,
      MROWS, 1024, 4096, 16, 0, 1);

  // combine: d_out = p0 + p1 + d_out(p2) + p3
  add4_kernel<<<dim3(MROWS * 1024 / 4 / 256), dim3(256), 0, stream>>>(
      (const float4*)p0, (const float4*)p1, (const float4*)d_out, (const float4*)p3,
      (float4*)d_out, MROWS * 1024 / 4);
}